// Round 3
// baseline (1064.246 us; speedup 1.0000x reference)
//
#include <hip/hip_runtime.h>
#include <hip/hip_bf16.h>

// TemporalAttention: B=8,T=128,N=64,K=8 heads,d=64,D=512
// H=[X|STE] [65536,1536] -> q,k,v = relu(H @ W^T + b) [65536,512] each
// per (head,b,n): S=q k^T/8, causal mask, softmax, O=P v
// out = relu(O @ Wo^T + bo)
// Round 6: GEMMs moved from the m97 128<U+00B2> structure (883 TF = its ceiling,
// MfmaUtil 40%) to the 256<U+00B2> deep-pipelined schedule (T3+T4+T5):
// 512 threads / 8 waves (2Mx4N), BK=64, 128 KB LDS double-buffer,
// per-wave 128x64 output. Per K-tile: 4 lockstep phases
// {ds_read -> lgkmcnt(0)+sched_barrier(0) -> setprio(1) -> 16 MFMA ->
//  setprio(0) -> s_barrier}. All 8 global_load_lds for tile t+1 issue at
// tile-t top into the idle buffer; wait is COUNTED vmcnt(8) (t+1's loads
// stay in flight across barriers; only the last tile drains to 0).
// Safety: each phase's ds_reads drain via lgkmcnt(0) BEFORE its MFMA, so
// all reads of a buffer are complete before any wave passes the phase
// barrier and restages it. Bank swizzle = round-5 scheme (row&7 XOR on
// 16B slots, pre-swizzled global source; measured 0 conflicts).
// Prepass + attention unchanged (verified passing).

typedef __attribute__((ext_vector_type(8))) short short8;     // 8 x bf16/f16 frag
typedef __attribute__((ext_vector_type(8))) _Float16 half8;   // 8 x f16 for MFMA
typedef __attribute__((ext_vector_type(4))) float floatx4;    // MFMA acc / 16B fp32 ld
typedef __attribute__((ext_vector_type(4))) unsigned int uintx4; // 16B ld/st

static __device__ __forceinline__ ushort f2b(float f) {
  __hip_bfloat16 h = __float2bfloat16(f);
  return __builtin_bit_cast(ushort, h);
}
static __device__ __forceinline__ ushort f2h(float f) {
  _Float16 h = (_Float16)f;
  return __builtin_bit_cast(ushort, h);
}
// exact bf16 -> fp32 unpack from a packed uint (2 bf16)
static __device__ __forceinline__ float blo(unsigned int w) {
  return __builtin_bit_cast(float, w << 16);
}
static __device__ __forceinline__ float bhi(unsigned int w) {
  return __builtin_bit_cast(float, w & 0xffff0000u);
}
// load 8 consecutive fp32, convert to 8 packed bf16 (2 x dwordx4 loads)
static __device__ __forceinline__ uintx4 cvt8(const float* __restrict__ p) {
  const floatx4 f0 = *(const floatx4*)(p);
  const floatx4 f1 = *(const floatx4*)(p + 4);
  uintx4 r;
  r[0] = (unsigned int)f2b(f0[0]) | ((unsigned int)f2b(f0[1]) << 16);
  r[1] = (unsigned int)f2b(f0[2]) | ((unsigned int)f2b(f0[3]) << 16);
  r[2] = (unsigned int)f2b(f1[0]) | ((unsigned int)f2b(f1[1]) << 16);
  r[3] = (unsigned int)f2b(f1[2]) | ((unsigned int)f2b(f1[3]) << 16);
  return r;
}
// async global->LDS, 16B per lane; LDS dest must be WAVE-UNIFORM base
// (HW writes lane l at base + l*16), global addr is per-lane.
static __device__ __forceinline__ void gld_lds16(const ushort* g, ushort* l) {
  __builtin_amdgcn_global_load_lds(
      (const __attribute__((address_space(1))) void*)g,
      (__attribute__((address_space(3))) void*)l, 16, 0, 0);
}

// ---------------------------------------------------------------------------
// Prepass: fp32 -> bf16 for H = [X | STE] and the four weight matrices.
// (unchanged from Round 5 — verified passing)
// ---------------------------------------------------------------------------
__global__ __launch_bounds__(256)
void cvt_bf16_pass(const float* __restrict__ X, const float* __restrict__ STE,
                   const float* __restrict__ Wq, const float* __restrict__ Wk,
                   const float* __restrict__ Wv, const float* __restrict__ Wo,
                   ushort* __restrict__ H, ushort* __restrict__ Wb,
                   ushort* __restrict__ Wob)
{
  const int stride = gridDim.x * blockDim.x;
  for (int c = blockIdx.x * blockDim.x + threadIdx.x; c < 12910592; c += stride) {
    const float* src; ushort* dst;
    if (c < 4194304) {
      const int m = c >> 6, col = (c & 63) << 3;
      src = X + ((size_t)c << 3);
      dst = H + (size_t)m * 1536 + col;
    } else if (c < 12582912) {
      const int c2 = c - 4194304;
      const int m = c2 >> 7, col = (c2 & 127) << 3;
      src = STE + ((size_t)c2 << 3);
      dst = H + (size_t)m * 1536 + 512 + col;
    } else if (c < 12877824) {
      const int c3 = c - 12582912;                 // 98304 chunks per W
      const int w = c3 / 98304;
      const int r = c3 - w * 98304;
      const float* Ws = (w == 0) ? Wq : (w == 1) ? Wk : Wv;
      src = Ws + ((size_t)r << 3);
      dst = Wb + ((size_t)c3 << 3);
    } else {
      const int c4 = c - 12877824;
      src = Wo + ((size_t)c4 << 3);
      dst = Wob + ((size_t)c4 << 3);
    }
    *(uintx4*)dst = cvt8(src);
  }
}

// ---------------------------------------------------------------------------
// 256x256 deep-pipelined bf16 GEMM (T3+T4+T5 schedule).
// C[m, cbase+o] = relu(sum_c A[m,c]*W[o,c] + bias[o]); A,W bf16 K-contig.
// 512 threads = 8 waves (wm=wave>>2 in {0,1}: M-half; wn=wave&3: N-quarter).
// LDS: As/Bs [2][256][64] bf16 (128 KB total), rows = 128 B of 8 16B slots,
// phys slot p of row r holds col-slot p^(r&7) (pre-swizzled global source;
// linear gld_lds dest; XOR on ds_read). TRIPLE: tn 0..5 -> {Wq,Wk,Wv} x 2
// tiles of 256, ldc=1536.
// ---------------------------------------------------------------------------
template<int KDIM, bool TRIPLE, bool OUT_F32>
__global__ __launch_bounds__(512, 2)
void gemm_bf16_8p(const ushort* __restrict__ A, const ushort* __restrict__ Wall,
                  const float* __restrict__ b0, const float* __restrict__ b1,
                  const float* __restrict__ b2, void* __restrict__ Cv, int ldc)
{
  __shared__ ushort As[2][256 * 64];   // 64 KB
  __shared__ ushort Bs[2][256 * 64];   // 64 KB

  const int tn = blockIdx.x, tm = blockIdx.y;
  const int tid = threadIdx.x;
  const int wave = tid >> 6, lane = tid & 63;
  const int quad = lane >> 4, lid = lane & 15;
  const int wm = wave >> 2, wn = wave & 3;

  const ushort* W; const float* bias; int nbase, cbase;
  if (TRIPLE) {
    const int seg = tn >> 1;
    W = Wall + (size_t)seg * 512 * KDIM;
    bias = (seg == 0) ? b0 : (seg == 1) ? b1 : b2;
    nbase = (tn & 1) * 256;
    cbase = seg * 512;
  } else { W = Wall; bias = b0; nbase = tn * 256; cbase = 0; }

  // staging geometry: issue i (0..3) per wave covers segments
  // [i*512 + wave*64, +64) = rows i*64+wave*8 .. +8, 8 slots each.
  // Lane l -> row +(l>>3), phys slot l&7; global col-slot = phys^(row&7).
  const int rloc = lane >> 3, sphys = lane & 7;
  const ushort* ga[4]; const ushort* gb[4]; int ldso[4];
#pragma unroll
  for (int i = 0; i < 4; i++) {
    const int row = i * 64 + wave * 8 + rloc;
    const int slog = sphys ^ (row & 7);
    ga[i] = A + (size_t)(tm * 256 + row) * KDIM + slog * 8;
    gb[i] = W + (size_t)(nbase + row) * KDIM + slog * 8;
    ldso[i] = (i * 512 + wave * 64) * 8;   // ushort offset of segment start
  }

  constexpr int NT = KDIM / 64;

  // prologue: stage tile 0 -> buf 0 (8 loads in flight)
#pragma unroll
  for (int i = 0; i < 4; i++) {
    gld_lds16(ga[i], &As[0][ldso[i]]);
    gld_lds16(gb[i], &Bs[0][ldso[i]]);
    ga[i] += 64; gb[i] += 64;
  }

  floatx4 acc[8][4];
#pragma unroll
  for (int i = 0; i < 8; i++)
#pragma unroll
    for (int j = 0; j < 4; j++) acc[i][j] = (floatx4){0.f, 0.f, 0.f, 0.f};

  int cur = 0;
  for (int t = 0; t < NT; ++t) {
    // stage tile t+1 into the idle buffer, then COUNTED wait for tile t:
    // t's 8 loads are the oldest; t+1's 8 stay in flight across barriers.
    if (t + 1 < NT) {
#pragma unroll
      for (int i = 0; i < 4; i++) {
        gld_lds16(ga[i], &As[cur ^ 1][ldso[i]]);
        gld_lds16(gb[i], &Bs[cur ^ 1][ldso[i]]);
        ga[i] += 64; gb[i] += 64;
      }
      asm volatile("s_waitcnt vmcnt(8)" ::: "memory");
    } else {
      asm volatile("s_waitcnt vmcnt(0)" ::: "memory");
    }
    __builtin_amdgcn_s_barrier();          // all waves' tile-t writes visible

    const char* asB = (const char*)As[cur];
    const char* bsB = (const char*)Bs[cur];
    short8 bfr[4], af[4];
    // 4 lockstep phases: (ks, m-half). B-frags read at mh==0, reused at mh==1.
#pragma unroll
    for (int ks = 0; ks < 2; ++ks) {
#pragma unroll
      for (int mh = 0; mh < 2; ++mh) {
        if (mh == 0) {
#pragma unroll
          for (int n = 0; n < 4; n++) {
            const int br = wn * 64 + n * 16 + lid;
            bfr[n] = *(const short8*)(bsB + br * 128 + (((ks * 4 + quad) ^ (lid & 7)) << 4));
          }
        }
#pragma unroll
        for (int m = 0; m < 4; m++) {
          const int ar = wm * 128 + (mh * 4 + m) * 16 + lid;
          af[m] = *(const short8*)(asB + ar * 128 + (((ks * 4 + quad) ^ (lid & 7)) << 4));
        }
        asm volatile("s_waitcnt lgkmcnt(0)" ::: "memory");
        __builtin_amdgcn_sched_barrier(0);   // rule 18: pin MFMA after the wait
        __builtin_amdgcn_s_setprio(1);
#pragma unroll
        for (int m = 0; m < 4; m++)
#pragma unroll
          for (int n = 0; n < 4; n++)
            acc[mh * 4 + m][n] = __builtin_amdgcn_mfma_f32_16x16x32_bf16(
                af[m], bfr[n], acc[mh * 4 + m][n], 0, 0, 0);
        __builtin_amdgcn_s_setprio(0);
        __builtin_amdgcn_s_barrier();        // lockstep; also protects restage
      }
    }
    cur ^= 1;
  }

  // ---- epilogue: C row = quad*4+reg, col = lane&15 (verified m89/m91 layout)
#pragma unroll
  for (int n = 0; n < 4; n++) {
    const int ncol = nbase + wn * 64 + n * 16 + lid;
    const float bv = bias[ncol];
    const int cg = cbase + ncol;
#pragma unroll
    for (int mi = 0; mi < 8; mi++) {
      const int mrow = tm * 256 + wm * 128 + mi * 16 + quad * 4;
#pragma unroll
      for (int r = 0; r < 4; r++) {
        float v = acc[mi][n][r] + bv;
        v = v > 0.f ? v : 0.f;
        if (OUT_F32) ((float*)Cv)[(size_t)(mrow + r) * ldc + cg] = v;
        else         ((ushort*)Cv)[(size_t)(mrow + r) * ldc + cg] = f2b(v);
      }
    }
  }
}

// ---------------------------------------------------------------------------
// MFMA flash-style attention (unchanged from Round 4 — verified passing).
// One block per (head,b,n); 4 waves, each wave owns 32 S-rows.
// ---------------------------------------------------------------------------
__global__ __launch_bounds__(256, 2)
void attn_mfma(const ushort* __restrict__ qkv, ushort* __restrict__ outb)
{
  __shared__ ushort Ks[128 * 64];    // 16 KB
  __shared__ ushort Vt[64 * 128];    // 16 KB
  __shared__ ushort Ps[128 * 128];   // 32 KB

  const int bx = blockIdx.x;
  const int head = bx >> 9;
  const int b = (bx >> 6) & 7;
  const int n = bx & 63;
  const int tid = threadIdx.x;
  const int wave = tid >> 6, lane = tid & 63;
  const int quad = lane >> 4, lid = lane & 15;

  char* KsB = (char*)Ks;
  char* VtB = (char*)Vt;
  char* PsB = (char*)Ps;

#pragma unroll
  for (int i = 0; i < 4; i++) {
    const int idx = tid + i * 256;          // 0..1023
    const int s = idx >> 3, slot = idx & 7;
    const ushort* gb = qkv + ((size_t)((b * 128 + s) * 64 + n)) * 1536 + head * 64;
    const uintx4 kw = *(const uintx4*)(gb + 512 + slot * 8);
    *(uintx4*)(KsB + s * 128 + ((slot ^ (s & 7)) << 4)) = kw;
    const uintx4 vw = *(const uintx4*)(gb + 1024 + slot * 8);
#pragma unroll
    for (int j = 0; j < 4; j++) {
      const int d0 = slot * 8 + 2 * j;
      const int d1 = d0 + 1;
      *(ushort*)(VtB + d0 * 256 + (((s >> 3) ^ (d0 & 15)) << 4) + (s & 7) * 2) = f2h(blo(vw[j]));
      *(ushort*)(VtB + d1 * 256 + (((s >> 3) ^ (d1 & 15)) << 4) + (s & 7) * 2) = f2h(bhi(vw[j]));
    }
  }

  short8 qf[2][2];
#pragma unroll
  for (int i = 0; i < 2; i++)
#pragma unroll
    for (int ks = 0; ks < 2; ks++) {
      const int t = wave * 32 + i * 16 + lid;
      qf[i][ks] = *(const short8*)(qkv + ((size_t)((b * 128 + t) * 64 + n)) * 1536
                                   + head * 64 + ks * 32 + quad * 8);
    }
  __syncthreads();

  floatx4 acc[2][8];
#pragma unroll
  for (int i = 0; i < 2; i++)
#pragma unroll
    for (int j = 0; j < 8; j++) acc[i][j] = (floatx4){0.f, 0.f, 0.f, 0.f};

#pragma unroll
  for (int ks = 0; ks < 2; ks++) {
#pragma unroll
    for (int j = 0; j < 8; j++) {
      const int srow = j * 16 + lid;
      const short8 kf = *(const short8*)(KsB + srow * 128
                                         + (((ks * 4 + quad) ^ (srow & 7)) << 4));
#pragma unroll
      for (int i = 0; i < 2; i++)
        acc[i][j] = __builtin_amdgcn_mfma_f32_16x16x32_bf16(qf[i][ks], kf, acc[i][j], 0, 0, 0);
    }
  }

  float sum[2][4];
#pragma unroll
  for (int i = 0; i < 2; i++)
#pragma unroll
    for (int r = 0; r < 4; r++) {
      const int row = wave * 32 + i * 16 + quad * 4 + r;
      float m = -1e30f;
#pragma unroll
      for (int j = 0; j < 8; j++) {
        const int col = j * 16 + lid;
        float sv = acc[i][j][r] * 0.125f;
        sv = (col > row) ? -1e30f : sv;   // causal mask (exp -> 0, matches NEG semantics)
        acc[i][j][r] = sv;
        m = fmaxf(m, sv);
      }
      m = fmaxf(m, __shfl_xor(m, 1));
      m = fmaxf(m, __shfl_xor(m, 2));
      m = fmaxf(m, __shfl_xor(m, 4));
      m = fmaxf(m, __shfl_xor(m, 8));
      float s = 0.f;
#pragma unroll
      for (int j = 0; j < 8; j++) {
        const float p = __expf(acc[i][j][r] - m);
        s += p;
        const int col = j * 16 + lid;
        *(ushort*)(PsB + row * 256 + (((col >> 3) ^ (row & 15)) << 4) + (col & 7) * 2) = f2h(p);
      }
      s += __shfl_xor(s, 1);
      s += __shfl_xor(s, 2);
      s += __shfl_xor(s, 4);
      s += __shfl_xor(s, 8);
      sum[i][r] = s;
    }
  __syncthreads();

  floatx4 acc2[2][4];
#pragma unroll
  for (int i = 0; i < 2; i++)
#pragma unroll
    for (int j2 = 0; j2 < 4; j2++) acc2[i][j2] = (floatx4){0.f, 0.f, 0.f, 0.f};

#pragma unroll
  for (int ks2 = 0; ks2 < 4; ks2++) {
    short8 pf[2];
#pragma unroll
    for (int i = 0; i < 2; i++) {
      const int row = wave * 32 + i * 16 + lid;
      pf[i] = *(const short8*)(PsB + row * 256 + (((ks2 * 4 + quad) ^ (row & 15)) << 4));
    }
#pragma unroll
    for (int j2 = 0; j2 < 4; j2++) {
      const int dd = j2 * 16 + lid;
      const short8 vf = *(const short8*)(VtB + dd * 256 + (((ks2 * 4 + quad) ^ (dd & 15)) << 4));
#pragma unroll
      for (int i = 0; i < 2; i++)
        acc2[i][j2] = __builtin_amdgcn_mfma_f32_16x16x32_f16(
            __builtin_bit_cast(half8, pf[i]), __builtin_bit_cast(half8, vf),
            acc2[i][j2], 0, 0, 0);
    }
  }

#pragma unroll
  for (int i = 0; i < 2; i++)
#pragma unroll
    for (int r = 0; r < 4; r++) {
      const float inv = 1.f / sum[i][r];
      const int t = wave * 32 + i * 16 + quad * 4 + r;
      ushort* ob = outb + ((size_t)((b * 128 + t) * 64 + n)) * 512 + head * 64;
#pragma unroll
      for (int j2 = 0; j2 < 4; j2++)
        ob[j2 * 16 + lid] = f2b(acc2[i][j2][r] * inv);
    }
}

extern "C" void kernel_launch(void* const* d_in, const int* in_sizes, int n_in,
                              void* d_out, int out_size, void* d_ws, size_t ws_size,
                              hipStream_t stream) {
  const float* X   = (const float*)d_in[0];   // [8,128,64,512]   fp32
  const float* STE = (const float*)d_in[1];   // [8,128,64,1024]  fp32
  const float* Wq  = (const float*)d_in[2];   // [512,1536]       fp32
  const float* bq  = (const float*)d_in[3];
  const float* Wk  = (const float*)d_in[4];
  const float* bk  = (const float*)d_in[5];
  const float* Wv  = (const float*)d_in[6];
  const float* bv  = (const float*)d_in[7];
  const float* Wo  = (const float*)d_in[8];   // [512,512]        fp32
  const float* bo  = (const float*)d_in[9];
  float* out = (float*)d_out;                 // [8,128,64,512]   fp32

  // workspace layout (~408 MB):
  ushort* qkv = (ushort*)d_ws;                       // [65536,1536] bf16, 201 MB
  ushort* H   = qkv + (size_t)65536 * 1536;          // [65536,1536] bf16, 201 MB
  ushort* att = H;                                   // [65536,512]  bf16 (aliases H:
                                                     //  H dead after GEMM1)
  ushort* Wb  = H + (size_t)65536 * 1536;            // [3,512,1536] bf16, 4.7 MB
  ushort* Wob = Wb + (size_t)3 * 512 * 1536;         // [512,512]    bf16, 0.5 MB

  // 0) fp32 -> bf16 prepass (H = [X|STE], weights)
  cvt_bf16_pass<<<2048, 256, 0, stream>>>(X, STE, Wq, Wk, Wv, Wo, H, Wb, Wob);
  // 1) fused QKV projection + ReLU (bf16 in, bf16 ws out), 256<U+00B2> 8-wave pipe
  gemm_bf16_8p<1536, true, false><<<dim3(6, 256), 512, 0, stream>>>(
      H, Wb, bq, bk, bv, qkv, 1536);
  // 2) causal attention per (head,b,n) — MFMA flash-style (bf16 ws in/out)
  attn_mfma<<<dim3(4096), 256, 0, stream>>>(qkv, att);
  // 3) output projection + ReLU (bf16 ws in, fp32 out), same pipe
  gemm_bf16_8p<512, false, true><<<dim3(2, 256), 512, 0, stream>>>(
      att, Wob, bo, nullptr, nullptr, out, 512);
}

// Round 5
// 965.054 us; speedup vs baseline: 1.1028x; 1.1028x over previous
//
#include <hip/hip_runtime.h>
#include <hip/hip_bf16.h>

// TemporalAttention: B=8,T=128,N=64,K=8 heads,d=64,D=512
// H=[X|STE] [65536,1536] -> q,k,v = relu(H @ W^T + b) [65536,512] each
// per (head,b,n): S=q k^T/8, causal mask, softmax, O=P v
// out = relu(O @ Wo^T + bo)
// Round 8 == Round 7 resubmit (R7 bench died on container acquisition, not
// kernel: no bench JSON / no verify result was produced; source re-audited
// for OOB — QKV_OUT max index = 65536*1536-1, attn reads in-bounds).
// R7 changes vs R6: (a) REVERT GEMMs to the verified R5 m97 structure (the
// R6 256^2 pipeline regressed: coarse burst-stage + 1-deep prefetch at
// 2 waves/SIMD = m196's bad variant). (b) THE VARIABLE: qkv workspace
// layout changed to attention-major [(b*64+n)*8+head][3][t=128][d=64] so
// each attn block reads ONE contiguous 48 KB region (old layout scattered
// 128B islands at 196KB stride across 12MB -> ~390us of random-grain HBM).
// GEMM1's epilogue writes the new layout. (c) prepass partitioned by
// block range (no per-thread region branching/div).
// Attention math, MFMA layouts, swizzles: unchanged (verified passing).

typedef __attribute__((ext_vector_type(8))) short short8;     // 8 x bf16/f16 frag
typedef __attribute__((ext_vector_type(8))) _Float16 half8;   // 8 x f16 for MFMA
typedef __attribute__((ext_vector_type(4))) float floatx4;    // MFMA acc / 16B fp32 ld
typedef __attribute__((ext_vector_type(4))) unsigned int uintx4; // 16B ld/st

static __device__ __forceinline__ ushort f2b(float f) {
  __hip_bfloat16 h = __float2bfloat16(f);
  return __builtin_bit_cast(ushort, h);
}
static __device__ __forceinline__ ushort f2h(float f) {
  _Float16 h = (_Float16)f;
  return __builtin_bit_cast(ushort, h);
}
// exact bf16 -> fp32 unpack from a packed uint (2 bf16)
static __device__ __forceinline__ float blo(unsigned int w) {
  return __builtin_bit_cast(float, w << 16);
}
static __device__ __forceinline__ float bhi(unsigned int w) {
  return __builtin_bit_cast(float, w & 0xffff0000u);
}
// load 8 consecutive fp32, convert to 8 packed bf16 (2 x dwordx4 loads)
static __device__ __forceinline__ uintx4 cvt8(const float* __restrict__ p) {
  const floatx4 f0 = *(const floatx4*)(p);
  const floatx4 f1 = *(const floatx4*)(p + 4);
  uintx4 r;
  r[0] = (unsigned int)f2b(f0[0]) | ((unsigned int)f2b(f0[1]) << 16);
  r[1] = (unsigned int)f2b(f0[2]) | ((unsigned int)f2b(f0[3]) << 16);
  r[2] = (unsigned int)f2b(f1[0]) | ((unsigned int)f2b(f1[1]) << 16);
  r[3] = (unsigned int)f2b(f1[2]) | ((unsigned int)f2b(f1[3]) << 16);
  return r;
}
// async global->LDS, 16B per lane; LDS dest must be WAVE-UNIFORM base
// (HW writes lane l at base + l*16), global addr is per-lane.
static __device__ __forceinline__ void gld_lds16(const ushort* g, ushort* l) {
  __builtin_amdgcn_global_load_lds(
      (const __attribute__((address_space(1))) void*)g,
      (__attribute__((address_space(3))) void*)l, 16, 0, 0);
}

// ---------------------------------------------------------------------------
// Prepass: fp32 -> bf16. Block-range partitioned (uniform control flow):
//   blocks [0,1024):    X   -> H[m][0..512)     (4.19M chunks of 8 floats)
//   blocks [1024,2048): STE -> H[m][512..1536)  (8.39M chunks)
//   blocks [2048,2176): Wq,Wk,Wv -> Wb ; Wo -> Wob (0.33M chunks)
// ---------------------------------------------------------------------------
__global__ __launch_bounds__(256)
void cvt_bf16_pass(const float* __restrict__ X, const float* __restrict__ STE,
                   const float* __restrict__ Wq, const float* __restrict__ Wk,
                   const float* __restrict__ Wv, const float* __restrict__ Wo,
                   ushort* __restrict__ H, ushort* __restrict__ Wb,
                   ushort* __restrict__ Wob)
{
  const int bid = blockIdx.x, tid = threadIdx.x;
  if (bid < 1024) {
    for (int c = bid * 256 + tid; c < 4194304; c += 1024 * 256) {
      const int m = c >> 6, col = (c & 63) << 3;
      *(uintx4*)(H + (size_t)m * 1536 + col) = cvt8(X + ((size_t)c << 3));
    }
  } else if (bid < 2048) {
    for (int c = (bid - 1024) * 256 + tid; c < 8388608; c += 1024 * 256) {
      const int m = c >> 7, col = (c & 127) << 3;
      *(uintx4*)(H + (size_t)m * 1536 + 512 + col) = cvt8(STE + ((size_t)c << 3));
    }
  } else {
    for (int c = (bid - 2048) * 256 + tid; c < 327680; c += 128 * 256) {
      if (c < 294912) {
        const int w = c / 98304, r = c - w * 98304;
        const float* Ws = (w == 0) ? Wq : (w == 1) ? Wk : Wv;
        *(uintx4*)(Wb + ((size_t)c << 3)) = cvt8(Ws + ((size_t)r << 3));
      } else {
        const int c4 = c - 294912;
        *(uintx4*)(Wob + ((size_t)c4 << 3)) = cvt8(Wo + ((size_t)c4 << 3));
      }
    }
  }
}

// ---------------------------------------------------------------------------
// C = relu(A @ W^T + bias); A,W bf16 K-contig. m97 structure (R5-verified):
// 128x128 tile, BK=64, 4 waves x (4x4) 16x16x32 bf16 MFMA, global_load_lds
// width=16 staging, linear LDS [128][64] bf16. Bank swizzle: phys slot p of
// row r holds col-slot p^(r&7) via pre-swizzled GLOBAL source + XOR on
// ds_read (rule 21; measured 0 conflicts).
// TRIPLE: n-tiles 0..11 -> {Wq,Wk,Wv} x 4 tiles of 128.
// QKV_OUT: write C in attention-major layout
//   qkv2[ ((b*64+n)*8+head)*3 + seg ][t*64 + dd]   (8192 ushorts per plane)
//   where m=(b*128+t)*64+n, channel = head*64+dd, seg = which of {q,k,v}.
// else: C[m][ldc] (fp32 if OUT_F32 else bf16).
// ---------------------------------------------------------------------------
template<int KDIM, bool TRIPLE, bool OUT_F32, bool QKV_OUT>
__global__ __launch_bounds__(256, 2)
void gemm_bf16_async(const ushort* __restrict__ A, const ushort* __restrict__ Wall,
                     const float* __restrict__ b0, const float* __restrict__ b1,
                     const float* __restrict__ b2, void* __restrict__ Cv, int ldc)
{
  __shared__ ushort As[128 * 64];   // 16 KB, linear
  __shared__ ushort Bs[128 * 64];   // 16 KB, linear

  const int tn = blockIdx.x, tm = blockIdx.y;
  const int tid = threadIdx.x;
  const int wave = tid >> 6, lane = tid & 63;
  const int quad = lane >> 4, lid = lane & 15;
  const int wm = wave >> 1, wn = wave & 1;

  const ushort* W; const float* bias; int nbase, cbase;
  if (TRIPLE) {
    const int seg = tn >> 2;
    W = Wall + (size_t)seg * 512 * 1536;
    bias = (seg == 0) ? b0 : (seg == 1) ? b1 : b2;
    nbase = (tn & 3) * 128;
    cbase = seg * 512;
  } else { W = Wall; bias = b0; nbase = tn * 128; cbase = 0; }

  // staging geometry: wave-issue i writes LDS bytes [(wave*4+i)*1024, +1024):
  // lane l -> row (wave*4+i)*8 + (l>>3), phys slot l&7. Source col-slot =
  // phys ^ (row&7).
  const int rloc = lane >> 3, sphys = lane & 7;

  floatx4 acc[4][4];
#pragma unroll
  for (int i = 0; i < 4; i++)
#pragma unroll
    for (int j = 0; j < 4; j++) acc[i][j] = (floatx4){0.f, 0.f, 0.f, 0.f};

  const char* AsB = (const char*)As;
  const char* BsB = (const char*)Bs;

  for (int kt = 0; kt < KDIM / 64; ++kt) {
#pragma unroll
    for (int i = 0; i < 4; i++) {
      const int row = (wave * 4 + i) * 8 + rloc;
      const int slog = sphys ^ (row & 7);
      const int k0 = kt * 64 + slog * 8;
      gld_lds16(A + (size_t)(tm * 128 + row) * KDIM + k0, As + (wave * 4 + i) * 512);
      gld_lds16(W + (size_t)(nbase + row) * KDIM + k0,    Bs + (wave * 4 + i) * 512);
    }
    __syncthreads();   // compiler drains vmcnt before s_barrier -> tiles ready
#pragma unroll
    for (int ks = 0; ks < 2; ++ks) {
      short8 af[4], bfr[4];
#pragma unroll
      for (int t = 0; t < 4; t++) {
        const int ar = wm * 64 + t * 16 + lid;
        const int br = wn * 64 + t * 16 + lid;
        af[t]  = *(const short8*)(AsB + ar * 128 + (((ks * 4 + quad) ^ (ar & 7)) << 4));
        bfr[t] = *(const short8*)(BsB + br * 128 + (((ks * 4 + quad) ^ (br & 7)) << 4));
      }
#pragma unroll
      for (int i = 0; i < 4; i++)
#pragma unroll
        for (int j = 0; j < 4; j++)
          acc[i][j] = __builtin_amdgcn_mfma_f32_16x16x32_bf16(af[i], bfr[j], acc[i][j], 0, 0, 0);
    }
    __syncthreads();
  }

  // ---- epilogue: C row = quad*4+reg, col = lane&15 (verified m89/m91 layout)
  float bvj[4];
#pragma unroll
  for (int j = 0; j < 4; j++) bvj[j] = bias[nbase + wn * 64 + j * 16 + lid];

  if (QKV_OUT) {
    // wave's 64-col slice is exactly one head: head fixed, dd = j*16+lid.
    const int head_w = (nbase + wn * 64) >> 6;
    const int seg = cbase >> 9;
#pragma unroll
    for (int i = 0; i < 4; i++) {
#pragma unroll
      for (int r = 0; r < 4; r++) {
        const int m = tm * 128 + wm * 64 + i * 16 + quad * 4 + r;
        const int b_ = m >> 13, t_ = (m >> 6) & 127, n_ = m & 63;
        ushort* rowp = (ushort*)Cv
            + ((((size_t)(b_ * 64 + n_) * 8 + head_w) * 3 + seg) << 13) + t_ * 64;
#pragma unroll
        for (int j = 0; j < 4; j++) {
          float v = acc[i][j][r] + bvj[j];
          v = v > 0.f ? v : 0.f;
          rowp[j * 16 + lid] = f2b(v);
        }
      }
    }
  } else {
#pragma unroll
    for (int j = 0; j < 4; j++) {
      const int cg = cbase + nbase + wn * 64 + j * 16 + lid;
#pragma unroll
      for (int i = 0; i < 4; i++) {
        const int mrow = tm * 128 + wm * 64 + i * 16 + quad * 4;
#pragma unroll
        for (int r = 0; r < 4; r++) {
          float v = acc[i][j][r] + bvj[j];
          v = v > 0.f ? v : 0.f;
          if (OUT_F32) ((float*)Cv)[(size_t)(mrow + r) * ldc + cg] = v;
          else         ((ushort*)Cv)[(size_t)(mrow + r) * ldc + cg] = f2b(v);
        }
      }
    }
  }
}

// ---------------------------------------------------------------------------
// MFMA flash-style attention. One block per (head,b,n); 4 waves.
// NEW: qkv2 layout [(b*64+n)*8+head][3][128][64] -> this block's q,k,v are
// ONE contiguous 48 KB region; staging loads are fully coalesced streams.
// All LDS swizzles / MFMA layout math unchanged (verified passing).
// ---------------------------------------------------------------------------
__global__ __launch_bounds__(256, 2)
void attn_mfma(const ushort* __restrict__ qkv2, ushort* __restrict__ outb)
{
  __shared__ ushort Ks[128 * 64];    // 16 KB
  __shared__ ushort Vt[64 * 128];    // 16 KB
  __shared__ ushort Ps[128 * 128];   // 32 KB

  const int bx = blockIdx.x;
  const int head = bx >> 9;
  const int b = (bx >> 6) & 7;
  const int n = bx & 63;
  const int tid = threadIdx.x;
  const int wave = tid >> 6, lane = tid & 63;
  const int quad = lane >> 4, lid = lane & 15;

  char* KsB = (char*)Ks;
  char* VtB = (char*)Vt;
  char* PsB = (char*)Ps;

  // contiguous base for this (b,n,head): [3][128][64] ushorts
  const ushort* base = qkv2 + (((size_t)(b * 64 + n) * 8 + head) * 3 << 13);

  // ---- stage K (bf16, swizzled) and V (transpose -> f16 Vt, swizzled)
#pragma unroll
  for (int i = 0; i < 4; i++) {
    const int idx = tid + i * 256;          // 0..1023
    const int s = idx >> 3, slot = idx & 7;
    const uintx4 kw = *(const uintx4*)(base + 8192 + s * 64 + slot * 8);
    *(uintx4*)(KsB + s * 128 + ((slot ^ (s & 7)) << 4)) = kw;
    const uintx4 vw = *(const uintx4*)(base + 16384 + s * 64 + slot * 8);
#pragma unroll
    for (int j = 0; j < 4; j++) {
      const int d0 = slot * 8 + 2 * j;
      const int d1 = d0 + 1;
      *(ushort*)(VtB + d0 * 256 + (((s >> 3) ^ (d0 & 15)) << 4) + (s & 7) * 2) = f2h(blo(vw[j]));
      *(ushort*)(VtB + d1 * 256 + (((s >> 3) ^ (d1 & 15)) << 4) + (s & 7) * 2) = f2h(bhi(vw[j]));
    }
  }

  // ---- q fragments direct from global (A-frag: row = lid, k = ks*32+quad*8)
  short8 qf[2][2];
#pragma unroll
  for (int i = 0; i < 2; i++)
#pragma unroll
    for (int ks = 0; ks < 2; ks++) {
      const int t = wave * 32 + i * 16 + lid;
      qf[i][ks] = *(const short8*)(base + t * 64 + ks * 32 + quad * 8);
    }
  __syncthreads();

  // ---- S = q k^T (bf16 MFMA): rows wave*32..+32, cols 0..127
  floatx4 acc[2][8];
#pragma unroll
  for (int i = 0; i < 2; i++)
#pragma unroll
    for (int j = 0; j < 8; j++) acc[i][j] = (floatx4){0.f, 0.f, 0.f, 0.f};

#pragma unroll
  for (int ks = 0; ks < 2; ks++) {
#pragma unroll
    for (int j = 0; j < 8; j++) {
      const int srow = j * 16 + lid;
      const short8 kf = *(const short8*)(KsB + srow * 128
                                         + (((ks * 4 + quad) ^ (srow & 7)) << 4));
#pragma unroll
      for (int i = 0; i < 2; i++)
        acc[i][j] = __builtin_amdgcn_mfma_f32_16x16x32_bf16(qf[i][ks], kf, acc[i][j], 0, 0, 0);
    }
  }

  // ---- scale + causal mask + wave-parallel softmax; P (f16) -> LDS
  float sum[2][4];
#pragma unroll
  for (int i = 0; i < 2; i++)
#pragma unroll
    for (int r = 0; r < 4; r++) {
      const int row = wave * 32 + i * 16 + quad * 4 + r;
      float m = -1e30f;
#pragma unroll
      for (int j = 0; j < 8; j++) {
        const int col = j * 16 + lid;
        float sv = acc[i][j][r] * 0.125f;
        sv = (col > row) ? -1e30f : sv;   // causal mask (exp -> 0, matches NEG semantics)
        acc[i][j][r] = sv;
        m = fmaxf(m, sv);
      }
      m = fmaxf(m, __shfl_xor(m, 1));
      m = fmaxf(m, __shfl_xor(m, 2));
      m = fmaxf(m, __shfl_xor(m, 4));
      m = fmaxf(m, __shfl_xor(m, 8));
      float s = 0.f;
#pragma unroll
      for (int j = 0; j < 8; j++) {
        const float p = __expf(acc[i][j][r] - m);
        s += p;
        const int col = j * 16 + lid;
        *(ushort*)(PsB + row * 256 + (((col >> 3) ^ (row & 15)) << 4) + (col & 7) * 2) = f2h(p);
      }
      s += __shfl_xor(s, 1);
      s += __shfl_xor(s, 2);
      s += __shfl_xor(s, 4);
      s += __shfl_xor(s, 8);
      sum[i][r] = s;
    }
  __syncthreads();

  // ---- O = P v (f16 MFMA)
  floatx4 acc2[2][4];
#pragma unroll
  for (int i = 0; i < 2; i++)
#pragma unroll
    for (int j2 = 0; j2 < 4; j2++) acc2[i][j2] = (floatx4){0.f, 0.f, 0.f, 0.f};

#pragma unroll
  for (int ks2 = 0; ks2 < 4; ks2++) {
    short8 pf[2];
#pragma unroll
    for (int i = 0; i < 2; i++) {
      const int row = wave * 32 + i * 16 + lid;
      pf[i] = *(const short8*)(PsB + row * 256 + (((ks2 * 4 + quad) ^ (row & 15)) << 4));
    }
#pragma unroll
    for (int j2 = 0; j2 < 4; j2++) {
      const int dd = j2 * 16 + lid;
      const short8 vf = *(const short8*)(VtB + dd * 256 + (((ks2 * 4 + quad) ^ (dd & 15)) << 4));
#pragma unroll
      for (int i = 0; i < 2; i++)
        acc2[i][j2] = __builtin_amdgcn_mfma_f32_16x16x32_f16(
            __builtin_bit_cast(half8, pf[i]), __builtin_bit_cast(half8, vf),
            acc2[i][j2], 0, 0, 0);
    }
  }

  // ---- normalize, write O (bf16 ws, [m][512] layout for GEMM3-A staging)
#pragma unroll
  for (int i = 0; i < 2; i++)
#pragma unroll
    for (int r = 0; r < 4; r++) {
      const float inv = 1.f / sum[i][r];
      const int t = wave * 32 + i * 16 + quad * 4 + r;
      ushort* ob = outb + ((size_t)((b * 128 + t) * 64 + n)) * 512 + head * 64;
#pragma unroll
      for (int j2 = 0; j2 < 4; j2++)
        ob[j2 * 16 + lid] = f2b(acc2[i][j2][r] * inv);
    }
}

extern "C" void kernel_launch(void* const* d_in, const int* in_sizes, int n_in,
                              void* d_out, int out_size, void* d_ws, size_t ws_size,
                              hipStream_t stream) {
  const float* X   = (const float*)d_in[0];   // [8,128,64,512]   fp32
  const float* STE = (const float*)d_in[1];   // [8,128,64,1024]  fp32
  const float* Wq  = (const float*)d_in[2];   // [512,1536]       fp32
  const float* bq  = (const float*)d_in[3];
  const float* Wk  = (const float*)d_in[4];
  const float* bk  = (const float*)d_in[5];
  const float* Wv  = (const float*)d_in[6];
  const float* bv  = (const float*)d_in[7];
  const float* Wo  = (const float*)d_in[8];   // [512,512]        fp32
  const float* bo  = (const float*)d_in[9];
  float* out = (float*)d_out;                 // [8,128,64,512]   fp32

  // workspace layout (~408 MB):
  ushort* qkv2 = (ushort*)d_ws;                      // [4096][3][128][64] bf16, 201 MB
  ushort* H    = qkv2 + (size_t)65536 * 1536;        // [65536,1536] bf16, 201 MB
  ushort* att  = H;                                  // [65536,512] bf16 (aliases H:
                                                     //  H dead after GEMM1)
  ushort* Wb  = H + (size_t)65536 * 1536;            // [3,512,1536] bf16, 4.7 MB
  ushort* Wob = Wb + (size_t)3 * 512 * 1536;         // [512,512]    bf16, 0.5 MB

  // 0) fp32 -> bf16 prepass (H = [X|STE], weights), block-range partitioned
  cvt_bf16_pass<<<2176, 256, 0, stream>>>(X, STE, Wq, Wk, Wv, Wo, H, Wb, Wob);
  // 1) fused QKV projection + ReLU -> attention-major qkv2 layout
  gemm_bf16_async<1536, true, false, true><<<dim3(12, 512), 256, 0, stream>>>(
      H, Wb, bq, bk, bv, qkv2, 0);
  // 2) causal attention per (head,b,n) — contiguous 48 KB reads per block
  attn_mfma<<<dim3(4096), 256, 0, stream>>>(qkv2, att);
  // 3) output projection + ReLU (bf16 ws in, fp32 out)
  gemm_bf16_async<512, false, true, false><<<dim3(4, 512), 256, 0, stream>>>(
      att, Wob, bo, nullptr, nullptr, out, 512);
}